// Round 5
// baseline (1009.631 us; speedup 1.0000x reference)
//
#include <hip/hip_runtime.h>
#include <hip/hip_bf16.h>
#include <math.h>

// Problem constants
#define NTOK 16384   // B*N = 4*4096
#define DM   1024
#define NQKV 3072
#define DFF  4096

typedef __bf16 bf16;
typedef __bf16 bf16x8 __attribute__((ext_vector_type(8)));
typedef float  f32x4  __attribute__((ext_vector_type(4)));

__device__ __forceinline__ void gload_lds16(const bf16* g, bf16* l) {
  __builtin_amdgcn_global_load_lds((const __attribute__((address_space(1))) void*)g,
                                   (__attribute__((address_space(3))) void*)l,
                                   16, 0, 0);
}

#define BAR()    asm volatile("s_barrier" ::: "memory")
#define SB0()    __builtin_amdgcn_sched_barrier(0)
#define LGKM(N)  asm volatile("s_waitcnt lgkmcnt(" #N ")" ::: "memory")
#define VMW(N)   asm volatile("s_waitcnt vmcnt(" #N ")" ::: "memory")

// ---------------- weight transpose + bf16 convert: src[K][N] fp32 -> dst[N][K] bf16 ----
__global__ __launch_bounds__(256)
void transpose_cvt(const float* __restrict__ src, bf16* __restrict__ dst, int K, int N)
{
  __shared__ float t[32][33];
  const int tx = threadIdx.x & 31, ty = threadIdx.x >> 5;
  const int n0 = blockIdx.x * 32, k0 = blockIdx.y * 32;
#pragma unroll
  for (int i = 0; i < 4; ++i)
    t[ty + 8*i][tx] = src[(size_t)(k0 + ty + 8*i) * N + n0 + tx];
  __syncthreads();
#pragma unroll
  for (int i = 0; i < 4; ++i)
    dst[(size_t)(n0 + ty + 8*i) * K + k0 + tx] = (bf16)t[tx][ty + 8*i];
}

__global__ void concat_bias(const float* __restrict__ bq, const float* __restrict__ bk,
                            const float* __restrict__ bv, float* __restrict__ o)
{
  int i = blockIdx.x * 256 + threadIdx.x;
  o[i] = (i < 1024) ? bq[i] : (i < 2048 ? bk[i - 1024] : bv[i - 2048]);
}

// ---------------- LayerNorm 1: x fp32 -> h bf16 --------------------------------------
__global__ __launch_bounds__(256)
void ln1_kernel(const float* __restrict__ x, const float* __restrict__ gamma,
                bf16* __restrict__ out)
{
  __shared__ float2 red[4];
  const int row = blockIdx.x, tid = threadIdx.x;
  const float4 v = ((const float4*)(x + (size_t)row * DM))[tid];
  float s  = v.x + v.y + v.z + v.w;
  float s2 = v.x*v.x + v.y*v.y + v.z*v.z + v.w*v.w;
#pragma unroll
  for (int m = 32; m >= 1; m >>= 1) { s += __shfl_xor(s, m); s2 += __shfl_xor(s2, m); }
  if ((tid & 63) == 0) red[tid >> 6] = make_float2(s, s2);
  __syncthreads();
  float S  = red[0].x + red[1].x + red[2].x + red[3].x;
  float S2 = red[0].y + red[1].y + red[2].y + red[3].y;
  const float mean = S * (1.0f / DM);
  const float var  = S2 * (1.0f / DM) - mean * mean;
  const float rs   = rsqrtf(var + 1e-5f);
  const float4 g = ((const float4*)gamma)[tid];
  union { bf16 b[4]; uint2 u; } o;
  o.b[0] = (bf16)((v.x - mean) * rs * g.x);
  o.b[1] = (bf16)((v.y - mean) * rs * g.y);
  o.b[2] = (bf16)((v.z - mean) * rs * g.z);
  o.b[3] = (bf16)((v.w - mean) * rs * g.w);
  *(uint2*)(out + (size_t)row * DM + tid * 4) = o.u;
}

// ---------------- LayerNorm 2 (double LN): xnew fp32 -> h2 bf16 ----------------------
__global__ __launch_bounds__(256)
void ln2_kernel(const float* __restrict__ x, const float* __restrict__ gamma,
                const float* __restrict__ ffg, const float* __restrict__ ffb,
                bf16* __restrict__ out)
{
  __shared__ float2 red[4];
  const int row = blockIdx.x, tid = threadIdx.x;
  const float4 v = ((const float4*)(x + (size_t)row * DM))[tid];
  float s  = v.x + v.y + v.z + v.w;
  float s2 = v.x*v.x + v.y*v.y + v.z*v.z + v.w*v.w;
#pragma unroll
  for (int m = 32; m >= 1; m >>= 1) { s += __shfl_xor(s, m); s2 += __shfl_xor(s2, m); }
  if ((tid & 63) == 0) red[tid >> 6] = make_float2(s, s2);
  __syncthreads();
  float S  = red[0].x + red[1].x + red[2].x + red[3].x;
  float S2 = red[0].y + red[1].y + red[2].y + red[3].y;
  float mean = S * (1.0f / DM);
  float var  = S2 * (1.0f / DM) - mean * mean;
  float rs   = rsqrtf(var + 1e-5f);
  const float4 g = ((const float4*)gamma)[tid];
  float y0 = (v.x - mean) * rs * g.x;
  float y1 = (v.y - mean) * rs * g.y;
  float y2 = (v.z - mean) * rs * g.z;
  float y3 = (v.w - mean) * rs * g.w;
  __syncthreads();  // red[] reuse
  s  = y0 + y1 + y2 + y3;
  s2 = y0*y0 + y1*y1 + y2*y2 + y3*y3;
#pragma unroll
  for (int m = 32; m >= 1; m >>= 1) { s += __shfl_xor(s, m); s2 += __shfl_xor(s2, m); }
  if ((tid & 63) == 0) red[tid >> 6] = make_float2(s, s2);
  __syncthreads();
  S  = red[0].x + red[1].x + red[2].x + red[3].x;
  S2 = red[0].y + red[1].y + red[2].y + red[3].y;
  mean = S * (1.0f / DM);
  var  = S2 * (1.0f / DM) - mean * mean;
  rs   = rsqrtf(var + 1e-5f);
  const float4 a = ((const float4*)ffg)[tid];
  const float4 bb = ((const float4*)ffb)[tid];
  union { bf16 b[4]; uint2 u; } o;
  o.b[0] = (bf16)((y0 - mean) * rs * a.x + bb.x);
  o.b[1] = (bf16)((y1 - mean) * rs * a.y + bb.y);
  o.b[2] = (bf16)((y2 - mean) * rs * a.z + bb.z);
  o.b[3] = (bf16)((y3 - mean) * rs * a.w + bb.w);
  *(uint2*)(out + (size_t)row * DM + tid * 4) = o.u;
}

// ======================= 256x256 read-ahead 4-phase GEMM ==============================
// C[M x N] = A[M x K](bf16,lda) @ Bt[N x K]^T + bias ; EPI 0 bf16, 1 fp32+res, 2 gelu bf16
// 8 waves (2M x 4N), BK=64, LDS 128KB. Quadrants Q00(af0,b0) Q01(af0,b1) Q10(af1,b0)
// Q11(af1,b1); each phase reads the frags needed ONE phase later (4/8/8/4 reads),
// stages one half-tile of K-tile t+2, uniform vmcnt(8) at ph1/ph3 boundaries.

#define A_OFF(buf, mh) (((buf)*2 + (mh)) * 8192)
#define B_OFF(buf, nh) (32768 + ((buf)*2 + (nh)) * 8192)

__device__ __forceinline__ void mmaq(f32x4 (&acc)[8][4], bf16x8 (&a)[4][2],
                                     bf16x8 (&b)[2][2], int mh, int nh)
{
  __builtin_amdgcn_s_setprio(1);
#pragma unroll
  for (int i = 0; i < 4; ++i)
#pragma unroll
    for (int j = 0; j < 2; ++j)
#pragma unroll
      for (int kk = 0; kk < 2; ++kk)
        acc[mh*4 + i][nh*2 + j] =
          __builtin_amdgcn_mfma_f32_16x16x32_bf16(a[i][kk], b[j][kk],
                                                  acc[mh*4 + i][nh*2 + j], 0, 0, 0);
  __builtin_amdgcn_s_setprio(0);
}

template<int EPI>
__global__ __launch_bounds__(512, 2)
void gemm256(const bf16* __restrict__ A, int lda,
             const bf16* __restrict__ Bt,
             const float* __restrict__ bias,
             const float* res, int ldres,
             void* Cout, int ldc, int K, int nblk)
{
  __shared__ __align__(16) bf16 lds[65536];   // 128 KB
  const int tid = threadIdx.x, lane = tid & 63, wave = tid >> 6;
  const int wm = wave >> 2, wn = wave & 3;
  const int l16 = lane & 15, lg = lane >> 4;

  // XCD-aware swizzle (nblk % 8 == 0 for all our grids); M always 16384 -> 64 row blocks
  int id = blockIdx.x;
  id = (id & 7) * (nblk >> 3) + (id >> 3);
  const int row0 = (id & 63) << 8;
  const int col0 = (id >> 6) << 8;
  const int NT = K >> 6;   // 16 / 48 / 64 — always even, >= 4

  // ---- staging byte offsets (advance += 128 per use) -------------------------------
  const char* Ab = (const char*)A;
  const char* Bb = (const char*)Bt;
  unsigned oA[2][2], oB[2][2];   // [hf][l]
  {
    const int lr = lane >> 3, lc = lane & 7;
#pragma unroll
    for (int l = 0; l < 2; ++l) {
      const int rho = (wave * 2 + l) * 8 + lr;
      const int gc = ((lc ^ (rho & 7)) << 3);
#pragma unroll
      for (int hf = 0; hf < 2; ++hf) {
        const int ga = (rho >> 6) * 128 + hf * 64 + (rho & 63);
        const int gb = (rho >> 5) * 64 + hf * 32 + (rho & 31);
        oA[hf][l] = (unsigned)(((row0 + ga) * lda + gc) * 2);
        oB[hf][l] = (unsigned)(((col0 + gb) * K + gc) * 2);
      }
    }
  }
  const int so = wave * 1024 + lane * 8;  // LDS element offset of this lane's DMA slot

#define STAGE_A(hf, OFF) do { \
    gload_lds16((const bf16*)(Ab + oA[hf][0]), (bf16*)lds + (OFF) + so); \
    gload_lds16((const bf16*)(Ab + oA[hf][1]), (bf16*)lds + (OFF) + so + 512); \
    oA[hf][0] += 128; oA[hf][1] += 128; } while (0)
#define STAGE_B(hf, OFF) do { \
    gload_lds16((const bf16*)(Bb + oB[hf][0]), (bf16*)lds + (OFF) + so); \
    gload_lds16((const bf16*)(Bb + oB[hf][1]), (bf16*)lds + (OFF) + so + 512); \
    oB[hf][0] += 128; oB[hf][1] += 128; } while (0)

  // ---- frag LDS element offsets (iteration-invariant, swizzle baked in) ------------
  int aoff[4][2], boff[2][2];
#pragma unroll
  for (int i = 0; i < 4; ++i) {
    const int rho = wm * 64 + i * 16 + l16;
#pragma unroll
    for (int kk = 0; kk < 2; ++kk)
      aoff[i][kk] = rho * 64 + (((kk * 4 + lg) ^ (rho & 7)) << 3);
  }
#pragma unroll
  for (int j = 0; j < 2; ++j) {
    const int rho = wn * 32 + j * 16 + l16;
#pragma unroll
    for (int kk = 0; kk < 2; ++kk)
      boff[j][kk] = rho * 64 + (((kk * 4 + lg) ^ (rho & 7)) << 3);
  }

#define LDAF(dst, OFF) do { \
    dst[0][0] = *(const bf16x8*)&lds[(OFF) + aoff[0][0]]; \
    dst[0][1] = *(const bf16x8*)&lds[(OFF) + aoff[0][1]]; \
    dst[1][0] = *(const bf16x8*)&lds[(OFF) + aoff[1][0]]; \
    dst[1][1] = *(const bf16x8*)&lds[(OFF) + aoff[1][1]]; \
    dst[2][0] = *(const bf16x8*)&lds[(OFF) + aoff[2][0]]; \
    dst[2][1] = *(const bf16x8*)&lds[(OFF) + aoff[2][1]]; \
    dst[3][0] = *(const bf16x8*)&lds[(OFF) + aoff[3][0]]; \
    dst[3][1] = *(const bf16x8*)&lds[(OFF) + aoff[3][1]]; } while (0)
#define LDBF(dst, OFF) do { \
    dst[0][0] = *(const bf16x8*)&lds[(OFF) + boff[0][0]]; \
    dst[0][1] = *(const bf16x8*)&lds[(OFF) + boff[0][1]]; \
    dst[1][0] = *(const bf16x8*)&lds[(OFF) + boff[1][0]]; \
    dst[1][1] = *(const bf16x8*)&lds[(OFF) + boff[1][1]]; } while (0)

  f32x4 acc[8][4] = {};
  bf16x8 af0[4][2], af1[4][2], b0[2][2], b1[2][2];

  // ---- prologue: stage K-tiles 0 and 1 fully; confirm tile0; preload af0/b0 --------
  STAGE_A(0, A_OFF(0, 0)); STAGE_B(0, B_OFF(0, 0));
  STAGE_A(1, A_OFF(0, 1)); STAGE_B(1, B_OFF(0, 1));
  STAGE_A(0, A_OFF(1, 0)); STAGE_B(0, B_OFF(1, 0));
  STAGE_A(1, A_OFF(1, 1)); STAGE_B(1, B_OFF(1, 1));
  VMW(8);   // tile0's 4 halves landed; tile1's 4 halves (8 loads) in flight
  BAR();
  LDAF(af0, A_OFF(0, 0));   // af0(0): 8 reads
  LDBF(b0,  B_OFF(0, 0));   // b0(0):  4 reads

  // Steady-state ledger (per tile t, buf=BUF, nb=BUF^1):
  //  lgkm entering ph0: af0n(8)+b0n(4)=12 (issued t-1.ph2/ph3)
  //  vmem entering ph0: tiles (t+1)'s 4 halves = 8 loads
  //  ph0: read b1(4); LGKM(4) [drain af0n,b0n -> Q00 inputs + frees A(b,0),B(b,0)];
  //       stage A0(t+2)->A(b,0); Q00; BAR
  //  ph1: read af1(8); LGKM(8) [drain b1]; stage B0(t+2)->B(b,0); Q01;
  //       VMW(8) [retire A0(t+1),B0(t+1)]; BAR
  //  ph2: read af0(t+1)(8) from A(nb,0); LGKM(8) [drain af1]; stage A1(t+2)->A(b,1);
  //       Q10; BAR
  //  ph3: read b0(t+1)(4) from B(nb,0); stage B1(t+2)->B(b,1); Q11;
  //       VMW(8) [retire A1(t+1),B1(t+1)]; BAR
#define FULL(BUF) do { \
    LDBF(b1, B_OFF(BUF, 1)); \
    LGKM(4); \
    STAGE_A(0, A_OFF(BUF, 0)); \
    SB0(); mmaq(acc, af0, b0, 0, 0); \
    BAR(); \
    LDAF(af1, A_OFF(BUF, 1)); \
    LGKM(8); \
    STAGE_B(0, B_OFF(BUF, 0)); \
    SB0(); mmaq(acc, af0, b1, 0, 1); \
    VMW(8); \
    BAR(); \
    LDAF(af0, A_OFF((BUF) ^ 1, 0)); \
    LGKM(8); \
    STAGE_A(1, A_OFF(BUF, 1)); \
    SB0(); mmaq(acc, af1, b0, 1, 0); \
    BAR(); \
    LDBF(b0, B_OFF((BUF) ^ 1, 0)); \
    STAGE_B(1, B_OFF(BUF, 1)); \
    SB0(); mmaq(acc, af1, b1, 1, 1); \
    VMW(8); \
    BAR(); } while (0)

  for (int t = 0; t < NT - 2; t += 2) {
    FULL(0);
    FULL(1);
  }

  // ---- tail tile NT-2 (buf 0): no stages; vmcnt 4 then 0 ---------------------------
  LDBF(b1, B_OFF(0, 1));
  LGKM(4); SB0(); mmaq(acc, af0, b0, 0, 0); BAR();
  LDAF(af1, A_OFF(0, 1));
  LGKM(8); SB0(); mmaq(acc, af0, b1, 0, 1); VMW(4); BAR();
  LDAF(af0, A_OFF(1, 0));
  LGKM(8); SB0(); mmaq(acc, af1, b0, 1, 0); BAR();
  LDBF(b0, B_OFF(1, 0));
  SB0(); mmaq(acc, af1, b1, 1, 1); VMW(0); BAR();

  // ---- tail tile NT-1 (buf 1): no stages, no future reads --------------------------
  LDBF(b1, B_OFF(1, 1));
  LGKM(4); SB0(); mmaq(acc, af0, b0, 0, 0); BAR();
  LDAF(af1, A_OFF(1, 1));
  LGKM(8); SB0(); mmaq(acc, af0, b1, 0, 1); BAR();
  LGKM(0); SB0(); mmaq(acc, af1, b0, 1, 0); BAR();
  SB0(); mmaq(acc, af1, b1, 1, 1);

  // ---- epilogue
#pragma unroll
  for (int i = 0; i < 8; ++i) {
    const int m0 = row0 + wm * 128 + (i >> 2) * 64 + (i & 3) * 16 + lg * 4;
#pragma unroll
    for (int j = 0; j < 4; ++j) {
      const int n = col0 + wn * 64 + (j >> 1) * 32 + (j & 1) * 16 + l16;
      const float bv = bias[n];
#pragma unroll
      for (int r = 0; r < 4; ++r) {
        const long m = m0 + r;
        float v = acc[i][j][r] + bv;
        if constexpr (EPI == 0) {
          ((bf16*)Cout)[m * ldc + n] = (bf16)v;
        } else if constexpr (EPI == 1) {
          ((float*)Cout)[m * ldc + n] = v + res[m * ldres + n];
        } else {
          float gl = 0.5f * v * (1.0f + erff(v * 0.70710678118654752f));
          ((bf16*)Cout)[m * ldc + n] = (bf16)gl;
        }
      }
    }
  }
}

// ---------------- dilated attention: one wave per (b, g, h) --------------------------
__global__ __launch_bounds__(64)
void attn_kernel(bf16* qkv)
{
  __shared__ bf16 Plds[32 * 32];
  __shared__ bf16 vT[64 * 32];
  const int blk = blockIdx.x;
  const int h = blk & 15;
  const int g = (blk >> 4) & 63;
  const int b = blk >> 10;
  const int par = h & 1;
  const int lane = threadIdx.x;
  const int l16 = lane & 15, lg = lane >> 4;
  const long base = ((long)b * 4096 + g * 64) * NQKV;

  bf16x8 qf[2][2], kf[2][2];
#pragma unroll
  for (int mb = 0; mb < 2; ++mb) {
    const int s = par + 2 * (mb * 16 + l16);
    const bf16* qrow = qkv + base + (long)s * NQKV + h * 64;
#pragma unroll
    for (int kk = 0; kk < 2; ++kk) {
      qf[mb][kk] = *(const bf16x8*)(qrow + kk * 32 + lg * 8);
      kf[mb][kk] = *(const bf16x8*)(qrow + 1024 + kk * 32 + lg * 8);
    }
  }

#pragma unroll
  for (int it = 0; it < 4; ++it) {
    const int kr  = it * 8 + (lane >> 3);
    const int dh0 = (lane & 7) * 8;
    const int s = par + 2 * kr;
    union { uint4 u; bf16 e[8]; } vv;
    vv.u = *(const uint4*)(qkv + base + (long)s * NQKV + 2048 + h * 64 + dh0);
#pragma unroll
    for (int j = 0; j < 8; ++j)
      vT[(dh0 + j) * 32 + kr] = vv.e[j];
  }

  f32x4 sc[2][2] = {};
#pragma unroll
  for (int mb = 0; mb < 2; ++mb)
#pragma unroll
    for (int nb = 0; nb < 2; ++nb)
#pragma unroll
      for (int kk = 0; kk < 2; ++kk)
        sc[mb][nb] = __builtin_amdgcn_mfma_f32_16x16x32_bf16(qf[mb][kk], kf[nb][kk], sc[mb][nb], 0, 0, 0);

  float pr[2][2][4];
#pragma unroll
  for (int mb = 0; mb < 2; ++mb)
#pragma unroll
    for (int r = 0; r < 4; ++r) {
      float a0 = sc[mb][0][r] * 0.125f, a1 = sc[mb][1][r] * 0.125f;
      float mx = fmaxf(a0, a1);
#pragma unroll
      for (int msk = 8; msk >= 1; msk >>= 1) mx = fmaxf(mx, __shfl_xor(mx, msk));
      float e0 = expf(a0 - mx), e1 = expf(a1 - mx);
      float sm = e0 + e1;
#pragma unroll
      for (int msk = 8; msk >= 1; msk >>= 1) sm += __shfl_xor(sm, msk);
      float inv = 1.0f / sm;
      pr[mb][0][r] = e0 * inv;
      pr[mb][1][r] = e1 * inv;
    }

  __syncthreads();
#pragma unroll
  for (int mb = 0; mb < 2; ++mb)
#pragma unroll
    for (int nb = 0; nb < 2; ++nb)
#pragma unroll
      for (int r = 0; r < 4; ++r)
        Plds[(mb * 16 + lg * 4 + r) * 32 + nb * 16 + l16] = (bf16)pr[mb][nb][r];
  __syncthreads();

  bf16x8 pa[2], vb[4];
#pragma unroll
  for (int mb = 0; mb < 2; ++mb)
    pa[mb] = *(const bf16x8*)&Plds[(mb * 16 + l16) * 32 + lg * 8];
#pragma unroll
  for (int nb = 0; nb < 4; ++nb)
    vb[nb] = *(const bf16x8*)&vT[(nb * 16 + l16) * 32 + lg * 8];
  f32x4 oc[2][4] = {};
#pragma unroll
  for (int mb = 0; mb < 2; ++mb)
#pragma unroll
    for (int nb = 0; nb < 4; ++nb)
      oc[mb][nb] = __builtin_amdgcn_mfma_f32_16x16x32_bf16(pa[mb], vb[nb], oc[mb][nb], 0, 0, 0);

#pragma unroll
  for (int mb = 0; mb < 2; ++mb)
#pragma unroll
    for (int nb = 0; nb < 4; ++nb)
#pragma unroll
      for (int r = 0; r < 4; ++r) {
        const int m = mb * 16 + lg * 4 + r;
        const int s = par + 2 * m;
        qkv[base + (long)s * NQKV + h * 64 + nb * 16 + l16] = (bf16)oc[mb][nb][r];
      }
  const uint4 z = make_uint4(0, 0, 0, 0);
#pragma unroll
  for (int it = 0; it < 4; ++it) {
    const int r2 = it * 8 + (lane >> 3);
    const int s = (1 - par) + 2 * r2;
    *(uint4*)(qkv + base + (long)s * NQKV + h * 64 + (lane & 7) * 8) = z;
  }
}

// ---------------- host-side orchestration --------------------------------------------
extern "C" void kernel_launch(void* const* d_in, const int* in_sizes, int n_in,
                              void* d_out, int out_size, void* d_ws, size_t ws_size,
                              hipStream_t stream)
{
  const float* x     = (const float*)d_in[0];
  const float* gamma = (const float*)d_in[1];
  const float* wq = (const float*)d_in[2];  const float* bq = (const float*)d_in[3];
  const float* wk = (const float*)d_in[4];  const float* bk = (const float*)d_in[5];
  const float* wv = (const float*)d_in[6];  const float* bv = (const float*)d_in[7];
  const float* wo = (const float*)d_in[8];  const float* bo = (const float*)d_in[9];
  const float* ffg = (const float*)d_in[10]; const float* ffb = (const float*)d_in[11];
  const float* w1 = (const float*)d_in[12]; const float* b1 = (const float*)d_in[13];
  const float* w2 = (const float*)d_in[14]; const float* b2 = (const float*)d_in[15];

  char* p = (char*)d_ws;
  bf16* Wqkv_t = (bf16*)p; p += (size_t)NQKV * DM * 2;
  bf16* Wo_t   = (bf16*)p; p += (size_t)DM * DM * 2;
  bf16* W1_t   = (bf16*)p; p += (size_t)DFF * DM * 2;
  bf16* W2_t   = (bf16*)p; p += (size_t)DM * DFF * 2;
  float* bqkv  = (float*)p; p += (size_t)NQKV * 4;
  bf16* hbuf   = (bf16*)p; p += (size_t)NTOK * DM * 2;
  bf16* qkv    = (bf16*)p; p += (size_t)NTOK * DFF * 2;
  float* xnew  = (float*)d_out;

  dim3 b256(256);
  transpose_cvt<<<dim3(32, 32),  b256, 0, stream>>>(wq, Wqkv_t,               DM, DM);
  transpose_cvt<<<dim3(32, 32),  b256, 0, stream>>>(wk, Wqkv_t + 1024 * 1024, DM, DM);
  transpose_cvt<<<dim3(32, 32),  b256, 0, stream>>>(wv, Wqkv_t + 2048 * 1024, DM, DM);
  transpose_cvt<<<dim3(32, 32),  b256, 0, stream>>>(wo, Wo_t, DM, DM);
  transpose_cvt<<<dim3(128, 32), b256, 0, stream>>>(w1, W1_t, DM, DFF);
  transpose_cvt<<<dim3(32, 128), b256, 0, stream>>>(w2, W2_t, DFF, DM);
  concat_bias<<<12, b256, 0, stream>>>(bq, bk, bv, bqkv);

  ln1_kernel<<<NTOK, b256, 0, stream>>>(x, gamma, hbuf);

  // QKV GEMM: h @ [wq|wk|wv] -> qkv bf16 [16384][3072]
  gemm256<0><<<dim3(768), 512, 0, stream>>>(
      hbuf, DM, Wqkv_t, bqkv, nullptr, 0, qkv, NQKV, DM, 768);

  attn_kernel<<<4096, dim3(64), 0, stream>>>(qkv);

  // WO GEMM + residual -> xnew fp32 (d_out)
  gemm256<1><<<dim3(256), 512, 0, stream>>>(
      qkv, NQKV, Wo_t, bo, x, DM, xnew, DM, DM, 256);

  ln2_kernel<<<NTOK, b256, 0, stream>>>(xnew, gamma, ffg, ffb, hbuf);

  // FFN1 + GELU -> g1 bf16 [16384][4096]
  gemm256<2><<<dim3(1024), 512, 0, stream>>>(
      hbuf, DM, W1_t, b1, nullptr, 0, qkv, DFF, DM, 1024);

  // FFN2 + residual -> d_out fp32
  gemm256<1><<<dim3(256), 512, 0, stream>>>(
      qkv, DFF, W2_t, b2, xnew, DM, (float*)d_out, DM, DFF, 256);
}

// Round 6
// 706.708 us; speedup vs baseline: 1.4286x; 1.4286x over previous
//
#include <hip/hip_runtime.h>
#include <hip/hip_bf16.h>
#include <math.h>

// Problem constants
#define NTOK 16384   // B*N = 4*4096
#define DM   1024
#define NQKV 3072
#define DFF  4096

typedef __bf16 bf16;
typedef __bf16 bf16x8 __attribute__((ext_vector_type(8)));
typedef float  f32x4  __attribute__((ext_vector_type(4)));

__device__ __forceinline__ void gload_lds16(const bf16* g, bf16* l) {
  __builtin_amdgcn_global_load_lds((const __attribute__((address_space(1))) void*)g,
                                   (__attribute__((address_space(3))) void*)l,
                                   16, 0, 0);
}

#define BAR()    asm volatile("s_barrier" ::: "memory")
#define SB0()    __builtin_amdgcn_sched_barrier(0)
#define LGKM(N)  asm volatile("s_waitcnt lgkmcnt(" #N ")" ::: "memory")
#define VMW(N)   asm volatile("s_waitcnt vmcnt(" #N ")" ::: "memory")

// ---------------- weight transpose + bf16 convert: src[K][N] fp32 -> dst[N][K] bf16 ----
__global__ __launch_bounds__(256)
void transpose_cvt(const float* __restrict__ src, bf16* __restrict__ dst, int K, int N)
{
  __shared__ float t[32][33];
  const int tx = threadIdx.x & 31, ty = threadIdx.x >> 5;
  const int n0 = blockIdx.x * 32, k0 = blockIdx.y * 32;
#pragma unroll
  for (int i = 0; i < 4; ++i)
    t[ty + 8*i][tx] = src[(size_t)(k0 + ty + 8*i) * N + n0 + tx];
  __syncthreads();
#pragma unroll
  for (int i = 0; i < 4; ++i)
    dst[(size_t)(n0 + ty + 8*i) * K + k0 + tx] = (bf16)t[tx][ty + 8*i];
}

__global__ void concat_bias(const float* __restrict__ bq, const float* __restrict__ bk,
                            const float* __restrict__ bv, float* __restrict__ o)
{
  int i = blockIdx.x * 256 + threadIdx.x;
  o[i] = (i < 1024) ? bq[i] : (i < 2048 ? bk[i - 1024] : bv[i - 2048]);
}

// ---------------- LayerNorm 1: x fp32 -> h bf16 --------------------------------------
__global__ __launch_bounds__(256)
void ln1_kernel(const float* __restrict__ x, const float* __restrict__ gamma,
                bf16* __restrict__ out)
{
  __shared__ float2 red[4];
  const int row = blockIdx.x, tid = threadIdx.x;
  const float4 v = ((const float4*)(x + (size_t)row * DM))[tid];
  float s  = v.x + v.y + v.z + v.w;
  float s2 = v.x*v.x + v.y*v.y + v.z*v.z + v.w*v.w;
#pragma unroll
  for (int m = 32; m >= 1; m >>= 1) { s += __shfl_xor(s, m); s2 += __shfl_xor(s2, m); }
  if ((tid & 63) == 0) red[tid >> 6] = make_float2(s, s2);
  __syncthreads();
  float S  = red[0].x + red[1].x + red[2].x + red[3].x;
  float S2 = red[0].y + red[1].y + red[2].y + red[3].y;
  const float mean = S * (1.0f / DM);
  const float var  = S2 * (1.0f / DM) - mean * mean;
  const float rs   = rsqrtf(var + 1e-5f);
  const float4 g = ((const float4*)gamma)[tid];
  union { bf16 b[4]; uint2 u; } o;
  o.b[0] = (bf16)((v.x - mean) * rs * g.x);
  o.b[1] = (bf16)((v.y - mean) * rs * g.y);
  o.b[2] = (bf16)((v.z - mean) * rs * g.z);
  o.b[3] = (bf16)((v.w - mean) * rs * g.w);
  *(uint2*)(out + (size_t)row * DM + tid * 4) = o.u;
}

// ---------------- LayerNorm 2 (double LN): xnew fp32 -> h2 bf16 ----------------------
__global__ __launch_bounds__(256)
void ln2_kernel(const float* __restrict__ x, const float* __restrict__ gamma,
                const float* __restrict__ ffg, const float* __restrict__ ffb,
                bf16* __restrict__ out)
{
  __shared__ float2 red[4];
  const int row = blockIdx.x, tid = threadIdx.x;
  const float4 v = ((const float4*)(x + (size_t)row * DM))[tid];
  float s  = v.x + v.y + v.z + v.w;
  float s2 = v.x*v.x + v.y*v.y + v.z*v.z + v.w*v.w;
#pragma unroll
  for (int m = 32; m >= 1; m >>= 1) { s += __shfl_xor(s, m); s2 += __shfl_xor(s2, m); }
  if ((tid & 63) == 0) red[tid >> 6] = make_float2(s, s2);
  __syncthreads();
  float S  = red[0].x + red[1].x + red[2].x + red[3].x;
  float S2 = red[0].y + red[1].y + red[2].y + red[3].y;
  float mean = S * (1.0f / DM);
  float var  = S2 * (1.0f / DM) - mean * mean;
  float rs   = rsqrtf(var + 1e-5f);
  const float4 g = ((const float4*)ffg)[tid];
  const float4 gg = ((const float4*)gamma)[tid];
  float y0 = (v.x - mean) * rs * gg.x;
  float y1 = (v.y - mean) * rs * gg.y;
  float y2 = (v.z - mean) * rs * gg.z;
  float y3 = (v.w - mean) * rs * gg.w;
  __syncthreads();  // red[] reuse
  s  = y0 + y1 + y2 + y3;
  s2 = y0*y0 + y1*y1 + y2*y2 + y3*y3;
#pragma unroll
  for (int m = 32; m >= 1; m >>= 1) { s += __shfl_xor(s, m); s2 += __shfl_xor(s2, m); }
  if ((tid & 63) == 0) red[tid >> 6] = make_float2(s, s2);
  __syncthreads();
  S  = red[0].x + red[1].x + red[2].x + red[3].x;
  S2 = red[0].y + red[1].y + red[2].y + red[3].y;
  mean = S * (1.0f / DM);
  var  = S2 * (1.0f / DM) - mean * mean;
  rs   = rsqrtf(var + 1e-5f);
  const float4 bb = ((const float4*)ffb)[tid];
  union { bf16 b[4]; uint2 u; } o;
  o.b[0] = (bf16)((y0 - mean) * rs * g.x + bb.x);
  o.b[1] = (bf16)((y1 - mean) * rs * g.y + bb.y);
  o.b[2] = (bf16)((y2 - mean) * rs * g.z + bb.z);
  o.b[3] = (bf16)((y3 - mean) * rs * g.w + bb.w);
  *(uint2*)(out + (size_t)row * DM + tid * 4) = o.u;
}

// ======================= 256x256 8-phase (m201-faithful) GEMM =========================
// C[M x N] = A[M x K](bf16,lda) @ Bt[N x K]^T + bias ; EPI 0 bf16, 1 fp32+res, 2 gelu bf16
// 8 waves (2M x 4N), BK=64, LDS 128KB. Per tile t (parity b): 4 phases, each
// {ds_read own frags; stage 1 freed half; BAR; lgkm(0); setprio MFMA quadrant; BAR}.
// vmcnt(6) once per tile at ph3 (3 half-tiles in flight). Reads: 12/4/8/0 per phase.

#define A_OFF(buf, mh) (((buf)*2 + (mh)) * 8192)
#define B_OFF(buf, nh) (32768 + ((buf)*2 + (nh)) * 8192)

__device__ __forceinline__ void mmaq(f32x4 (&acc)[8][4], bf16x8 (&a)[4][2],
                                     bf16x8 (&b)[2][2], int mh, int nh)
{
  __builtin_amdgcn_s_setprio(1);
#pragma unroll
  for (int i = 0; i < 4; ++i)
#pragma unroll
    for (int j = 0; j < 2; ++j)
#pragma unroll
      for (int kk = 0; kk < 2; ++kk)
        acc[mh*4 + i][nh*2 + j] =
          __builtin_amdgcn_mfma_f32_16x16x32_bf16(a[i][kk], b[j][kk],
                                                  acc[mh*4 + i][nh*2 + j], 0, 0, 0);
  __builtin_amdgcn_s_setprio(0);
}

template<int EPI>
__global__ __launch_bounds__(512, 1)
void gemm256(const bf16* __restrict__ A, int lda,
             const bf16* __restrict__ Bt,
             const float* __restrict__ bias,
             const float* res, int ldres,
             void* Cout, int ldc, int K, int nblk)
{
  __shared__ __align__(16) bf16 lds[65536];   // 128 KB
  const int tid = threadIdx.x, lane = tid & 63, wave = tid >> 6;
  const int wm = wave >> 2, wn = wave & 3;
  const int l16 = lane & 15, lg = lane >> 4;

  // XCD-aware swizzle (nblk % 8 == 0 for all our grids); M always 16384 -> 64 row blocks
  int id = blockIdx.x;
  id = (id & 7) * (nblk >> 3) + (id >> 3);
  const int row0 = (id & 63) << 8;
  const int col0 = (id >> 6) << 8;
  const int NT = K >> 6;   // 16 or 64 — always even, >= 4

  // ---- staging byte offsets (advance += 128 per use) -------------------------------
  const char* Ab = (const char*)A;
  const char* Bb = (const char*)Bt;
  unsigned oA[2][2], oB[2][2];   // [hf][l]
  {
    const int lr = lane >> 3, lc = lane & 7;
#pragma unroll
    for (int l = 0; l < 2; ++l) {
      const int rho = (wave * 2 + l) * 8 + lr;
      const int gc = ((lc ^ (rho & 7)) << 3);
#pragma unroll
      for (int hf = 0; hf < 2; ++hf) {
        const int ga = (rho >> 6) * 128 + hf * 64 + (rho & 63);
        const int gb = (rho >> 5) * 64 + hf * 32 + (rho & 31);
        oA[hf][l] = (unsigned)(((row0 + ga) * lda + gc) * 2);
        oB[hf][l] = (unsigned)(((col0 + gb) * K + gc) * 2);
      }
    }
  }
  const int so = wave * 1024 + lane * 8;  // LDS element offset of this lane's DMA slot

#define STAGE_A(hf, OFF) do { \
    gload_lds16((const bf16*)(Ab + oA[hf][0]), (bf16*)lds + (OFF) + so); \
    gload_lds16((const bf16*)(Ab + oA[hf][1]), (bf16*)lds + (OFF) + so + 512); \
    oA[hf][0] += 128; oA[hf][1] += 128; } while (0)
#define STAGE_B(hf, OFF) do { \
    gload_lds16((const bf16*)(Bb + oB[hf][0]), (bf16*)lds + (OFF) + so); \
    gload_lds16((const bf16*)(Bb + oB[hf][1]), (bf16*)lds + (OFF) + so + 512); \
    oB[hf][0] += 128; oB[hf][1] += 128; } while (0)

  // ---- frag LDS element offsets (iteration-invariant, swizzle baked in) ------------
  int aoff[4][2], boff[2][2];
#pragma unroll
  for (int i = 0; i < 4; ++i) {
    const int rho = wm * 64 + i * 16 + l16;
#pragma unroll
    for (int kk = 0; kk < 2; ++kk)
      aoff[i][kk] = rho * 64 + (((kk * 4 + lg) ^ (rho & 7)) << 3);
  }
#pragma unroll
  for (int j = 0; j < 2; ++j) {
    const int rho = wn * 32 + j * 16 + l16;
#pragma unroll
    for (int kk = 0; kk < 2; ++kk)
      boff[j][kk] = rho * 64 + (((kk * 4 + lg) ^ (rho & 7)) << 3);
  }

#define LDAF(dst, OFF) do { \
    dst[0][0] = *(const bf16x8*)&lds[(OFF) + aoff[0][0]]; \
    dst[0][1] = *(const bf16x8*)&lds[(OFF) + aoff[0][1]]; \
    dst[1][0] = *(const bf16x8*)&lds[(OFF) + aoff[1][0]]; \
    dst[1][1] = *(const bf16x8*)&lds[(OFF) + aoff[1][1]]; \
    dst[2][0] = *(const bf16x8*)&lds[(OFF) + aoff[2][0]]; \
    dst[2][1] = *(const bf16x8*)&lds[(OFF) + aoff[2][1]]; \
    dst[3][0] = *(const bf16x8*)&lds[(OFF) + aoff[3][0]]; \
    dst[3][1] = *(const bf16x8*)&lds[(OFF) + aoff[3][1]]; } while (0)
#define LDBF(dst, OFF) do { \
    dst[0][0] = *(const bf16x8*)&lds[(OFF) + boff[0][0]]; \
    dst[0][1] = *(const bf16x8*)&lds[(OFF) + boff[0][1]]; \
    dst[1][0] = *(const bf16x8*)&lds[(OFF) + boff[1][0]]; \
    dst[1][1] = *(const bf16x8*)&lds[(OFF) + boff[1][1]]; } while (0)

  f32x4 acc[8][4] = {};
  bf16x8 af[4][2], b0[2][2], b1[2][2];

  // ---- prologue (m201): stage tile0 (8 loads), vmcnt(4); stage 3 halves of tile1,
  //      vmcnt(6) -> tile0 fully landed, 3 halves of tile1 in flight; BAR.
  STAGE_A(0, A_OFF(0, 0)); STAGE_B(0, B_OFF(0, 0));
  STAGE_A(1, A_OFF(0, 1)); STAGE_B(1, B_OFF(0, 1));
  VMW(4);
  STAGE_A(0, A_OFF(1, 0)); STAGE_B(0, B_OFF(1, 0)); STAGE_A(1, A_OFF(1, 1));
  VMW(6);
  BAR();

  // Per-tile ledger (tile TI, parity BUF, NB=BUF^1):
  //  entering: all 4 halves of TI confirmed; A(NB,0),B(NB,0),A(NB,1) of TI+1 in flight
  //  ph0: read af(A(BUF,0)) + b0(B(BUF,0)) [12]; stage B(NB,1)<-TI+1; LGKM(8);
  //       BAR; LGKM(0); Q00; BAR          [A(BUF,0),B(BUF,0) readers drained here]
  //  ph1: read b1(B(BUF,1)) [4]; stage A(BUF,0)<-TI+2; BAR; LGKM(0); Q01; BAR
  //  ph2: read af(A(BUF,1)) [8]; stage B(BUF,0)<-TI+2; BAR; LGKM(0); Q10; BAR
  //  ph3: stage A(BUF,1)<-TI+2; BAR; Q11; VMW(6) [TI+1 confirmed, 3 of TI+2 in
  //       flight]; BAR
  //  Every stage targets a region whose readers drained >=1 barrier earlier.
#define TILE8(BUF, TI) do { \
    const bool p1_ = (TI) + 1 < NT, p2_ = (TI) + 2 < NT; \
    LDAF(af, A_OFF(BUF, 0)); \
    LDBF(b0, B_OFF(BUF, 0)); \
    if (p1_) STAGE_B(1, B_OFF((BUF) ^ 1, 1)); \
    LGKM(8); \
    BAR(); \
    LGKM(0); SB0(); \
    mmaq(acc, af, b0, 0, 0); \
    BAR(); \
    LDBF(b1, B_OFF(BUF, 1)); \
    if (p2_) STAGE_A(0, A_OFF(BUF, 0)); \
    BAR(); \
    LGKM(0); SB0(); \
    mmaq(acc, af, b1, 0, 1); \
    BAR(); \
    LDAF(af, A_OFF(BUF, 1)); \
    if (p2_) STAGE_B(0, B_OFF(BUF, 0)); \
    BAR(); \
    LGKM(0); SB0(); \
    mmaq(acc, af, b0, 1, 0); \
    BAR(); \
    if (p2_) STAGE_A(1, A_OFF(BUF, 1)); \
    BAR(); \
    SB0(); \
    mmaq(acc, af, b1, 1, 1); \
    if (p2_) { VMW(6); } else if (p1_) { VMW(0); } \
    BAR(); } while (0)

  for (int t = 0; t < NT; t += 2) {
    TILE8(0, t);
    TILE8(1, t + 1);
  }

  // ---- epilogue
#pragma unroll
  for (int i = 0; i < 8; ++i) {
    const int m0 = row0 + wm * 128 + (i >> 2) * 64 + (i & 3) * 16 + lg * 4;
#pragma unroll
    for (int j = 0; j < 4; ++j) {
      const int n = col0 + wn * 64 + (j >> 1) * 32 + (j & 1) * 16 + l16;
      const float bv = bias[n];
#pragma unroll
      for (int r = 0; r < 4; ++r) {
        const long m = m0 + r;
        float v = acc[i][j][r] + bv;
        if constexpr (EPI == 0) {
          ((bf16*)Cout)[m * ldc + n] = (bf16)v;
        } else if constexpr (EPI == 1) {
          ((float*)Cout)[m * ldc + n] = v + res[m * ldres + n];
        } else {
          float gl = 0.5f * v * (1.0f + erff(v * 0.70710678118654752f));
          ((bf16*)Cout)[m * ldc + n] = (bf16)gl;
        }
      }
    }
  }
}

// ---------------- dilated attention: one wave per (b, g, h) --------------------------
__global__ __launch_bounds__(64)
void attn_kernel(bf16* qkv)
{
  __shared__ bf16 Plds[32 * 32];
  __shared__ bf16 vT[64 * 32];
  const int blk = blockIdx.x;
  const int h = blk & 15;
  const int g = (blk >> 4) & 63;
  const int b = blk >> 10;
  const int par = h & 1;
  const int lane = threadIdx.x;
  const int l16 = lane & 15, lg = lane >> 4;
  const long base = ((long)b * 4096 + g * 64) * NQKV;

  bf16x8 qf[2][2], kf[2][2];
#pragma unroll
  for (int mb = 0; mb < 2; ++mb) {
    const int s = par + 2 * (mb * 16 + l16);
    const bf16* qrow = qkv + base + (long)s * NQKV + h * 64;
#pragma unroll
    for (int kk = 0; kk < 2; ++kk) {
      qf[mb][kk] = *(const bf16x8*)(qrow + kk * 32 + lg * 8);
      kf[mb][kk] = *(const bf16x8*)(qrow + 1024 + kk * 32 + lg * 8);
    }
  }

#pragma unroll
  for (int it = 0; it < 4; ++it) {
    const int kr  = it * 8 + (lane >> 3);
    const int dh0 = (lane & 7) * 8;
    const int s = par + 2 * kr;
    union { uint4 u; bf16 e[8]; } vv;
    vv.u = *(const uint4*)(qkv + base + (long)s * NQKV + 2048 + h * 64 + dh0);
#pragma unroll
    for (int j = 0; j < 8; ++j)
      vT[(dh0 + j) * 32 + kr] = vv.e[j];
  }

  f32x4 sc[2][2] = {};
#pragma unroll
  for (int mb = 0; mb < 2; ++mb)
#pragma unroll
    for (int nb = 0; nb < 2; ++nb)
#pragma unroll
      for (int kk = 0; kk < 2; ++kk)
        sc[mb][nb] = __builtin_amdgcn_mfma_f32_16x16x32_bf16(qf[mb][kk], kf[nb][kk], sc[mb][nb], 0, 0, 0);

  float pr[2][2][4];
#pragma unroll
  for (int mb = 0; mb < 2; ++mb)
#pragma unroll
    for (int r = 0; r < 4; ++r) {
      float a0 = sc[mb][0][r] * 0.125f, a1 = sc[mb][1][r] * 0.125f;
      float mx = fmaxf(a0, a1);
#pragma unroll
      for (int msk = 8; msk >= 1; msk >>= 1) mx = fmaxf(mx, __shfl_xor(mx, msk));
      float e0 = expf(a0 - mx), e1 = expf(a1 - mx);
      float sm = e0 + e1;
#pragma unroll
      for (int msk = 8; msk >= 1; msk >>= 1) sm += __shfl_xor(sm, msk);
      float inv = 1.0f / sm;
      pr[mb][0][r] = e0 * inv;
      pr[mb][1][r] = e1 * inv;
    }

  __syncthreads();
#pragma unroll
  for (int mb = 0; mb < 2; ++mb)
#pragma unroll
    for (int nb = 0; nb < 2; ++nb)
#pragma unroll
      for (int r = 0; r < 4; ++r)
        Plds[(mb * 16 + lg * 4 + r) * 32 + nb * 16 + l16] = (bf16)pr[mb][nb][r];
  __syncthreads();

  bf16x8 pa[2], vb[4];
#pragma unroll
  for (int mb = 0; mb < 2; ++mb)
    pa[mb] = *(const bf16x8*)&Plds[(mb * 16 + l16) * 32 + lg * 8];
#pragma unroll
  for (int nb = 0; nb < 4; ++nb)
    vb[nb] = *(const bf16x8*)&vT[(nb * 16 + l16) * 32 + lg * 8];
  f32x4 oc[2][4] = {};
#pragma unroll
  for (int mb = 0; mb < 2; ++mb)
#pragma unroll
    for (int nb = 0; nb < 4; ++nb)
      oc[mb][nb] = __builtin_amdgcn_mfma_f32_16x16x32_bf16(pa[mb], vb[nb], oc[mb][nb], 0, 0, 0);

#pragma unroll
  for (int mb = 0; mb < 2; ++mb)
#pragma unroll
    for (int nb = 0; nb < 4; ++nb)
#pragma unroll
      for (int r = 0; r < 4; ++r) {
        const int m = mb * 16 + lg * 4 + r;
        const int s = par + 2 * m;
        qkv[base + (long)s * NQKV + h * 64 + nb * 16 + l16] = (bf16)oc[mb][nb][r];
      }
  const uint4 z = make_uint4(0, 0, 0, 0);
#pragma unroll
  for (int it = 0; it < 4; ++it) {
    const int r2 = it * 8 + (lane >> 3);
    const int s = (1 - par) + 2 * r2;
    *(uint4*)(qkv + base + (long)s * NQKV + h * 64 + (lane & 7) * 8) = z;
  }
}

// ---------------- host-side orchestration --------------------------------------------
extern "C" void kernel_launch(void* const* d_in, const int* in_sizes, int n_in,
                              void* d_out, int out_size, void* d_ws, size_t ws_size,
                              hipStream_t stream)
{
  const float* x     = (const float*)d_in[0];
  const float* gamma = (const float*)d_in[1];
  const float* wq = (const float*)d_in[2];  const float* bq = (const float*)d_in[3];
  const float* wk = (const float*)d_in[4];  const float* bk = (const float*)d_in[5];
  const float* wv = (const float*)d_in[6];  const float* bv = (const float*)d_in[7];
  const float* wo = (const float*)d_in[8];  const float* bo = (const float*)d_in[9];
  const float* ffg = (const float*)d_in[10]; const float* ffb = (const float*)d_in[11];
  const float* w1 = (const float*)d_in[12]; const float* b1 = (const float*)d_in[13];
  const float* w2 = (const float*)d_in[14]; const float* b2 = (const float*)d_in[15];

  char* p = (char*)d_ws;
  bf16* Wqkv_t = (bf16*)p; p += (size_t)NQKV * DM * 2;
  bf16* Wo_t   = (bf16*)p; p += (size_t)DM * DM * 2;
  bf16* W1_t   = (bf16*)p; p += (size_t)DFF * DM * 2;
  bf16* W2_t   = (bf16*)p; p += (size_t)DM * DFF * 2;
  float* bqkv  = (float*)p; p += (size_t)NQKV * 4;
  bf16* hbuf   = (bf16*)p; p += (size_t)NTOK * DM * 2;
  bf16* qkv    = (bf16*)p; p += (size_t)NTOK * DFF * 2;
  float* xnew  = (float*)d_out;

  dim3 b256(256);
  transpose_cvt<<<dim3(32, 32),  b256, 0, stream>>>(wq, Wqkv_t,               DM, DM);
  transpose_cvt<<<dim3(32, 32),  b256, 0, stream>>>(wk, Wqkv_t + 1024 * 1024, DM, DM);
  transpose_cvt<<<dim3(32, 32),  b256, 0, stream>>>(wv, Wqkv_t + 2048 * 1024, DM, DM);
  transpose_cvt<<<dim3(32, 32),  b256, 0, stream>>>(wo, Wo_t, DM, DM);
  transpose_cvt<<<dim3(128, 32), b256, 0, stream>>>(w1, W1_t, DM, DFF);
  transpose_cvt<<<dim3(32, 128), b256, 0, stream>>>(w2, W2_t, DFF, DM);
  concat_bias<<<12, b256, 0, stream>>>(bq, bk, bv, bqkv);

  ln1_kernel<<<NTOK, b256, 0, stream>>>(x, gamma, hbuf);

  // QKV GEMM: h @ [wq|wk|wv] -> qkv bf16 [16384][3072]
  gemm256<0><<<dim3(768), 512, 0, stream>>>(
      hbuf, DM, Wqkv_t, bqkv, nullptr, 0, qkv, NQKV, DM, 768);

  attn_kernel<<<4096, dim3(64), 0, stream>>>(qkv);

  // WO GEMM + residual -> xnew fp32 (d_out)
  gemm256<1><<<dim3(256), 512, 0, stream>>>(
      qkv, NQKV, Wo_t, bo, x, DM, xnew, DM, DM, 256);

  ln2_kernel<<<NTOK, b256, 0, stream>>>(xnew, gamma, ffg, ffb, hbuf);

  // FFN1 + GELU -> g1 bf16 [16384][4096]
  gemm256<2><<<dim3(1024), 512, 0, stream>>>(
      hbuf, DM, W1_t, b1, nullptr, 0, qkv, DFF, DM, 1024);

  // FFN2 + residual -> d_out fp32
  gemm256<1><<<dim3(256), 512, 0, stream>>>(
      qkv, DFF, W2_t, b2, xnew, DM, (float*)d_out, DM, DFF, 256);
}

// Round 7
// 685.676 us; speedup vs baseline: 1.4725x; 1.0307x over previous
//
#include <hip/hip_runtime.h>
#include <hip/hip_bf16.h>
#include <math.h>

// Problem constants
#define NTOK 16384   // B*N = 4*4096
#define DM   1024
#define NQKV 3072
#define DFF  4096

typedef __bf16 bf16;
typedef __bf16 bf16x8 __attribute__((ext_vector_type(8)));
typedef float  f32x4  __attribute__((ext_vector_type(4)));

__device__ __forceinline__ void gload_lds16(const bf16* g, bf16* l) {
  __builtin_amdgcn_global_load_lds((const __attribute__((address_space(1))) void*)g,
                                   (__attribute__((address_space(3))) void*)l,
                                   16, 0, 0);
}

// ---------------- weight transpose + bf16 convert: src[K][N] fp32 -> dst[N][K] bf16 ----
__global__ __launch_bounds__(256)
void transpose_cvt(const float* __restrict__ src, bf16* __restrict__ dst, int K, int N)
{
  __shared__ float t[32][33];
  const int tx = threadIdx.x & 31, ty = threadIdx.x >> 5;
  const int n0 = blockIdx.x * 32, k0 = blockIdx.y * 32;
#pragma unroll
  for (int i = 0; i < 4; ++i)
    t[ty + 8*i][tx] = src[(size_t)(k0 + ty + 8*i) * N + n0 + tx];
  __syncthreads();
#pragma unroll
  for (int i = 0; i < 4; ++i)
    dst[(size_t)(n0 + ty + 8*i) * K + k0 + tx] = (bf16)t[tx][ty + 8*i];
}

__global__ void concat_bias(const float* __restrict__ bq, const float* __restrict__ bk,
                            const float* __restrict__ bv, float* __restrict__ o)
{
  int i = blockIdx.x * 256 + threadIdx.x;
  o[i] = (i < 1024) ? bq[i] : (i < 2048 ? bk[i - 1024] : bv[i - 2048]);
}

// ---------------- LayerNorm 1: x fp32 -> h bf16 --------------------------------------
__global__ __launch_bounds__(256)
void ln1_kernel(const float* __restrict__ x, const float* __restrict__ gamma,
                bf16* __restrict__ out)
{
  __shared__ float2 red[4];
  const int row = blockIdx.x, tid = threadIdx.x;
  const float4 v = ((const float4*)(x + (size_t)row * DM))[tid];
  float s  = v.x + v.y + v.z + v.w;
  float s2 = v.x*v.x + v.y*v.y + v.z*v.z + v.w*v.w;
#pragma unroll
  for (int m = 32; m >= 1; m >>= 1) { s += __shfl_xor(s, m); s2 += __shfl_xor(s2, m); }
  if ((tid & 63) == 0) red[tid >> 6] = make_float2(s, s2);
  __syncthreads();
  float S  = red[0].x + red[1].x + red[2].x + red[3].x;
  float S2 = red[0].y + red[1].y + red[2].y + red[3].y;
  const float mean = S * (1.0f / DM);
  const float var  = S2 * (1.0f / DM) - mean * mean;
  const float rs   = rsqrtf(var + 1e-5f);
  const float4 g = ((const float4*)gamma)[tid];
  union { bf16 b[4]; uint2 u; } o;
  o.b[0] = (bf16)((v.x - mean) * rs * g.x);
  o.b[1] = (bf16)((v.y - mean) * rs * g.y);
  o.b[2] = (bf16)((v.z - mean) * rs * g.z);
  o.b[3] = (bf16)((v.w - mean) * rs * g.w);
  *(uint2*)(out + (size_t)row * DM + tid * 4) = o.u;
}

// ---------------- LayerNorm 2 (double LN): xnew fp32 -> h2 bf16 ----------------------
__global__ __launch_bounds__(256)
void ln2_kernel(const float* __restrict__ x, const float* __restrict__ gamma,
                const float* __restrict__ ffg, const float* __restrict__ ffb,
                bf16* __restrict__ out)
{
  __shared__ float2 red[4];
  const int row = blockIdx.x, tid = threadIdx.x;
  const float4 v = ((const float4*)(x + (size_t)row * DM))[tid];
  float s  = v.x + v.y + v.z + v.w;
  float s2 = v.x*v.x + v.y*v.y + v.z*v.z + v.w*v.w;
#pragma unroll
  for (int m = 32; m >= 1; m >>= 1) { s += __shfl_xor(s, m); s2 += __shfl_xor(s2, m); }
  if ((tid & 63) == 0) red[tid >> 6] = make_float2(s, s2);
  __syncthreads();
  float S  = red[0].x + red[1].x + red[2].x + red[3].x;
  float S2 = red[0].y + red[1].y + red[2].y + red[3].y;
  float mean = S * (1.0f / DM);
  float var  = S2 * (1.0f / DM) - mean * mean;
  float rs   = rsqrtf(var + 1e-5f);
  const float4 g = ((const float4*)ffg)[tid];
  const float4 gg = ((const float4*)gamma)[tid];
  float y0 = (v.x - mean) * rs * gg.x;
  float y1 = (v.y - mean) * rs * gg.y;
  float y2 = (v.z - mean) * rs * gg.z;
  float y3 = (v.w - mean) * rs * gg.w;
  __syncthreads();  // red[] reuse
  s  = y0 + y1 + y2 + y3;
  s2 = y0*y0 + y1*y1 + y2*y2 + y3*y3;
#pragma unroll
  for (int m = 32; m >= 1; m >>= 1) { s += __shfl_xor(s, m); s2 += __shfl_xor(s2, m); }
  if ((tid & 63) == 0) red[tid >> 6] = make_float2(s, s2);
  __syncthreads();
  S  = red[0].x + red[1].x + red[2].x + red[3].x;
  S2 = red[0].y + red[1].y + red[2].y + red[3].y;
  mean = S * (1.0f / DM);
  var  = S2 * (1.0f / DM) - mean * mean;
  rs   = rsqrtf(var + 1e-5f);
  const float4 bb = ((const float4*)ffb)[tid];
  union { bf16 b[4]; uint2 u; } o;
  o.b[0] = (bf16)((y0 - mean) * rs * g.x + bb.x);
  o.b[1] = (bf16)((y1 - mean) * rs * g.y + bb.y);
  o.b[2] = (bf16)((y2 - mean) * rs * g.z + bb.z);
  o.b[3] = (bf16)((y3 - mean) * rs * g.w + bb.w);
  *(uint2*)(out + (size_t)row * DM + tid * 4) = o.u;
}

// ======================= 128x128 m97-style GEMM (+swizzle, multi-block overlap) =======
// C[M x N] = A[M x K](bf16,lda) @ Bt[N x K]^T + bias ; EPI 0 bf16, 1 fp32+res, 2 gelu bf16
// 4 waves (2M x 2N), BK=64, single 32KB LDS buffer, 2 barriers/K-tile. Latency hiding
// comes from 3-5 independent blocks/CU (cross-block overlap), not intra-block pipelining.
// LDS swizzle: 16B granule g of row r stored from global granule g^(r&7); reads XOR same.

template<int EPI>
__global__ __launch_bounds__(256, 3)
void gemm128(const bf16* __restrict__ A, int lda,
             const bf16* __restrict__ Bt,
             const float* __restrict__ bias,
             const float* res, int ldres,
             void* Cout, int ldc, int K, int nblk)
{
  __shared__ __align__(16) bf16 lds[16384];   // 32 KB: A[128][64] | B[128][64]
  const int tid = threadIdx.x, lane = tid & 63, wave = tid >> 6;
  const int wm = wave >> 1, wn = wave & 1;
  const int l16 = lane & 15, lg = lane >> 4;

  // XCD-aware swizzle (nblk % 8 == 0); M = 16384 -> 128 row blocks
  int id = blockIdx.x;
  id = (id & 7) * (nblk >> 3) + (id >> 3);
  const int row0 = (id & 127) << 7;
  const int col0 = (id >> 7) << 7;
  const int NT = K >> 6;

  // ---- staging byte offsets (4 A-loads + 4 B-loads per thread; advance += 128 B) ----
  const char* Ab = (const char*)A;
  const char* Bb = (const char*)Bt;
  unsigned oA[4], oB[4];
  {
    const int lr = tid >> 3;          // 0..31 base row
    const int lc = tid & 7;           // granule slot
#pragma unroll
    for (int it = 0; it < 4; ++it) {
      const int r = it * 32 + lr;     // tile row 0..127
      const int gc = ((lc ^ (r & 7)) << 3);   // pre-swizzled source granule
      oA[it] = (unsigned)(((row0 + r) * lda + gc) * 2);
      oB[it] = (unsigned)(((col0 + r) * K   + gc) * 2);
    }
  }

#define STAGE() do { \
    gload_lds16((const bf16*)(Ab + oA[0]), lds        + tid * 8); \
    gload_lds16((const bf16*)(Ab + oA[1]), lds + 2048 + tid * 8); \
    gload_lds16((const bf16*)(Ab + oA[2]), lds + 4096 + tid * 8); \
    gload_lds16((const bf16*)(Ab + oA[3]), lds + 6144 + tid * 8); \
    gload_lds16((const bf16*)(Bb + oB[0]), lds + 8192 + tid * 8); \
    gload_lds16((const bf16*)(Bb + oB[1]), lds + 10240 + tid * 8); \
    gload_lds16((const bf16*)(Bb + oB[2]), lds + 12288 + tid * 8); \
    gload_lds16((const bf16*)(Bb + oB[3]), lds + 14336 + tid * 8); \
    oA[0] += 128; oA[1] += 128; oA[2] += 128; oA[3] += 128; \
    oB[0] += 128; oB[1] += 128; oB[2] += 128; oB[3] += 128; } while (0)

  // ---- frag LDS element offsets (iteration-invariant, swizzle baked in) ------------
  int aoff[4][2], boff[4][2];
#pragma unroll
  for (int i = 0; i < 4; ++i) {
    const int ra = wm * 64 + i * 16 + l16;
    const int rb = wn * 64 + i * 16 + l16;
#pragma unroll
    for (int kk = 0; kk < 2; ++kk) {
      aoff[i][kk] = ra * 64 + (((kk * 4 + lg) ^ (ra & 7)) << 3);
      boff[i][kk] = 8192 + rb * 64 + (((kk * 4 + lg) ^ (rb & 7)) << 3);
    }
  }

  f32x4 acc[4][4] = {};

  STAGE();                      // tile 0
  for (int t = 0; t < NT; ++t) {
    __syncthreads();            // drains vmcnt(0): tile t landed in LDS
    bf16x8 af[4][2], bf[4][2];
#pragma unroll
    for (int i = 0; i < 4; ++i) {
      af[i][0] = *(const bf16x8*)&lds[aoff[i][0]];
      af[i][1] = *(const bf16x8*)&lds[aoff[i][1]];
      bf[i][0] = *(const bf16x8*)&lds[boff[i][0]];
      bf[i][1] = *(const bf16x8*)&lds[boff[i][1]];
    }
#pragma unroll
    for (int i = 0; i < 4; ++i)
#pragma unroll
      for (int j = 0; j < 4; ++j)
#pragma unroll
        for (int kk = 0; kk < 2; ++kk)
          acc[i][j] = __builtin_amdgcn_mfma_f32_16x16x32_bf16(af[i][kk], bf[j][kk],
                                                              acc[i][j], 0, 0, 0);
    __syncthreads();            // all waves done reading tile t
    if (t + 1 < NT) STAGE();
  }

  // ---- epilogue: per wave 64x64 at (row0+wm*64, col0+wn*64) ------------------------
#pragma unroll
  for (int i = 0; i < 4; ++i) {
    const int m0 = row0 + wm * 64 + i * 16 + lg * 4;
#pragma unroll
    for (int j = 0; j < 4; ++j) {
      const int n = col0 + wn * 64 + j * 16 + l16;
      const float bv = bias[n];
#pragma unroll
      for (int r = 0; r < 4; ++r) {
        const long m = m0 + r;
        float v = acc[i][j][r] + bv;
        if constexpr (EPI == 0) {
          ((bf16*)Cout)[m * ldc + n] = (bf16)v;
        } else if constexpr (EPI == 1) {
          ((float*)Cout)[m * ldc + n] = v + res[m * ldres + n];
        } else {
          float gl = 0.5f * v * (1.0f + erff(v * 0.70710678118654752f));
          ((bf16*)Cout)[m * ldc + n] = (bf16)gl;
        }
      }
    }
  }
}

// ---------------- dilated attention: one wave per (b, g, h) --------------------------
__global__ __launch_bounds__(64)
void attn_kernel(bf16* qkv)
{
  __shared__ bf16 Plds[32 * 32];
  __shared__ bf16 vT[64 * 32];
  const int blk = blockIdx.x;
  const int h = blk & 15;
  const int g = (blk >> 4) & 63;
  const int b = blk >> 10;
  const int par = h & 1;
  const int lane = threadIdx.x;
  const int l16 = lane & 15, lg = lane >> 4;
  const long base = ((long)b * 4096 + g * 64) * NQKV;

  bf16x8 qf[2][2], kf[2][2];
#pragma unroll
  for (int mb = 0; mb < 2; ++mb) {
    const int s = par + 2 * (mb * 16 + l16);
    const bf16* qrow = qkv + base + (long)s * NQKV + h * 64;
#pragma unroll
    for (int kk = 0; kk < 2; ++kk) {
      qf[mb][kk] = *(const bf16x8*)(qrow + kk * 32 + lg * 8);
      kf[mb][kk] = *(const bf16x8*)(qrow + 1024 + kk * 32 + lg * 8);
    }
  }

#pragma unroll
  for (int it = 0; it < 4; ++it) {
    const int kr  = it * 8 + (lane >> 3);
    const int dh0 = (lane & 7) * 8;
    const int s = par + 2 * kr;
    union { uint4 u; bf16 e[8]; } vv;
    vv.u = *(const uint4*)(qkv + base + (long)s * NQKV + 2048 + h * 64 + dh0);
#pragma unroll
    for (int j = 0; j < 8; ++j)
      vT[(dh0 + j) * 32 + kr] = vv.e[j];
  }

  f32x4 sc[2][2] = {};
#pragma unroll
  for (int mb = 0; mb < 2; ++mb)
#pragma unroll
    for (int nb = 0; nb < 2; ++nb)
#pragma unroll
      for (int kk = 0; kk < 2; ++kk)
        sc[mb][nb] = __builtin_amdgcn_mfma_f32_16x16x32_bf16(qf[mb][kk], kf[nb][kk], sc[mb][nb], 0, 0, 0);

  float pr[2][2][4];
#pragma unroll
  for (int mb = 0; mb < 2; ++mb)
#pragma unroll
    for (int r = 0; r < 4; ++r) {
      float a0 = sc[mb][0][r] * 0.125f, a1 = sc[mb][1][r] * 0.125f;
      float mx = fmaxf(a0, a1);
#pragma unroll
      for (int msk = 8; msk >= 1; msk >>= 1) mx = fmaxf(mx, __shfl_xor(mx, msk));
      float e0 = expf(a0 - mx), e1 = expf(a1 - mx);
      float sm = e0 + e1;
#pragma unroll
      for (int msk = 8; msk >= 1; msk >>= 1) sm += __shfl_xor(sm, msk);
      float inv = 1.0f / sm;
      pr[mb][0][r] = e0 * inv;
      pr[mb][1][r] = e1 * inv;
    }

  __syncthreads();
#pragma unroll
  for (int mb = 0; mb < 2; ++mb)
#pragma unroll
    for (int nb = 0; nb < 2; ++nb)
#pragma unroll
      for (int r = 0; r < 4; ++r)
        Plds[(mb * 16 + lg * 4 + r) * 32 + nb * 16 + l16] = (bf16)pr[mb][nb][r];
  __syncthreads();

  bf16x8 pa[2], vb[4];
#pragma unroll
  for (int mb = 0; mb < 2; ++mb)
    pa[mb] = *(const bf16x8*)&Plds[(mb * 16 + l16) * 32 + lg * 8];
#pragma unroll
  for (int nb = 0; nb < 4; ++nb)
    vb[nb] = *(const bf16x8*)&vT[(nb * 16 + l16) * 32 + lg * 8];
  f32x4 oc[2][4] = {};
#pragma unroll
  for (int mb = 0; mb < 2; ++mb)
#pragma unroll
    for (int nb = 0; nb < 4; ++nb)
      oc[mb][nb] = __builtin_amdgcn_mfma_f32_16x16x32_bf16(pa[mb], vb[nb], oc[mb][nb], 0, 0, 0);

#pragma unroll
  for (int mb = 0; mb < 2; ++mb)
#pragma unroll
    for (int nb = 0; nb < 4; ++nb)
#pragma unroll
      for (int r = 0; r < 4; ++r) {
        const int m = mb * 16 + lg * 4 + r;
        const int s = par + 2 * m;
        qkv[base + (long)s * NQKV + h * 64 + nb * 16 + l16] = (bf16)oc[mb][nb][r];
      }
  const uint4 z = make_uint4(0, 0, 0, 0);
#pragma unroll
  for (int it = 0; it < 4; ++it) {
    const int r2 = it * 8 + (lane >> 3);
    const int s = (1 - par) + 2 * r2;
    *(uint4*)(qkv + base + (long)s * NQKV + h * 64 + (lane & 7) * 8) = z;
  }
}

// ---------------- host-side orchestration --------------------------------------------
extern "C" void kernel_launch(void* const* d_in, const int* in_sizes, int n_in,
                              void* d_out, int out_size, void* d_ws, size_t ws_size,
                              hipStream_t stream)
{
  const float* x     = (const float*)d_in[0];
  const float* gamma = (const float*)d_in[1];
  const float* wq = (const float*)d_in[2];  const float* bq = (const float*)d_in[3];
  const float* wk = (const float*)d_in[4];  const float* bk = (const float*)d_in[5];
  const float* wv = (const float*)d_in[6];  const float* bv = (const float*)d_in[7];
  const float* wo = (const float*)d_in[8];  const float* bo = (const float*)d_in[9];
  const float* ffg = (const float*)d_in[10]; const float* ffb = (const float*)d_in[11];
  const float* w1 = (const float*)d_in[12]; const float* b1 = (const float*)d_in[13];
  const float* w2 = (const float*)d_in[14]; const float* b2 = (const float*)d_in[15];

  char* p = (char*)d_ws;
  bf16* Wqkv_t = (bf16*)p; p += (size_t)NQKV * DM * 2;
  bf16* Wo_t   = (bf16*)p; p += (size_t)DM * DM * 2;
  bf16* W1_t   = (bf16*)p; p += (size_t)DFF * DM * 2;
  bf16* W2_t   = (bf16*)p; p += (size_t)DM * DFF * 2;
  float* bqkv  = (float*)p; p += (size_t)NQKV * 4;
  bf16* hbuf   = (bf16*)p; p += (size_t)NTOK * DM * 2;
  bf16* qkv    = (bf16*)p; p += (size_t)NTOK * DFF * 2;
  float* xnew  = (float*)d_out;

  dim3 b256(256);
  transpose_cvt<<<dim3(32, 32),  b256, 0, stream>>>(wq, Wqkv_t,               DM, DM);
  transpose_cvt<<<dim3(32, 32),  b256, 0, stream>>>(wk, Wqkv_t + 1024 * 1024, DM, DM);
  transpose_cvt<<<dim3(32, 32),  b256, 0, stream>>>(wv, Wqkv_t + 2048 * 1024, DM, DM);
  transpose_cvt<<<dim3(32, 32),  b256, 0, stream>>>(wo, Wo_t, DM, DM);
  transpose_cvt<<<dim3(128, 32), b256, 0, stream>>>(w1, W1_t, DM, DFF);
  transpose_cvt<<<dim3(32, 128), b256, 0, stream>>>(w2, W2_t, DFF, DM);
  concat_bias<<<12, b256, 0, stream>>>(bq, bk, bv, bqkv);

  ln1_kernel<<<NTOK, b256, 0, stream>>>(x, gamma, hbuf);

  // QKV GEMM: h @ [wq|wk|wv] -> qkv bf16 [16384][3072]
  gemm128<0><<<dim3(128 * 24), b256, 0, stream>>>(
      hbuf, DM, Wqkv_t, bqkv, nullptr, 0, qkv, NQKV, DM, 128 * 24);

  attn_kernel<<<4096, dim3(64), 0, stream>>>(qkv);

  // WO GEMM + residual -> xnew fp32 (d_out)
  gemm128<1><<<dim3(128 * 8), b256, 0, stream>>>(
      qkv, NQKV, Wo_t, bo, x, DM, xnew, DM, DM, 128 * 8);

  ln2_kernel<<<NTOK, b256, 0, stream>>>(xnew, gamma, ffg, ffb, hbuf);

  // FFN1 + GELU -> g1 bf16 [16384][4096]
  gemm128<2><<<dim3(128 * 32), b256, 0, stream>>>(
      hbuf, DM, W1_t, b1, nullptr, 0, qkv, DFF, DM, 128 * 32);

  // FFN2 + residual -> d_out fp32
  gemm128<1><<<dim3(128 * 8), b256, 0, stream>>>(
      qkv, DFF, W2_t, b2, xnew, DM, (float*)d_out, DM, DFF, 128 * 8);
}

// Round 8
// 679.615 us; speedup vs baseline: 1.4856x; 1.0089x over previous
//
#include <hip/hip_runtime.h>
#include <hip/hip_bf16.h>
#include <math.h>

// Problem constants
#define NTOK 16384   // B*N = 4*4096
#define DM   1024
#define NQKV 3072
#define DFF  4096

typedef __bf16 bf16;
typedef __bf16 bf16x8 __attribute__((ext_vector_type(8)));
typedef float  f32x4  __attribute__((ext_vector_type(4)));

__device__ __forceinline__ void gload_lds16(const bf16* g, bf16* l) {
  __builtin_amdgcn_global_load_lds((const __attribute__((address_space(1))) void*)g,
                                   (__attribute__((address_space(3))) void*)l,
                                   16, 0, 0);
}

// ---------------- weight transpose + bf16 convert: src[K][N] fp32 -> dst[N][K] bf16 ----
__global__ __launch_bounds__(256)
void transpose_cvt(const float* __restrict__ src, bf16* __restrict__ dst, int K, int N)
{
  __shared__ float t[32][33];
  const int tx = threadIdx.x & 31, ty = threadIdx.x >> 5;
  const int n0 = blockIdx.x * 32, k0 = blockIdx.y * 32;
#pragma unroll
  for (int i = 0; i < 4; ++i)
    t[ty + 8*i][tx] = src[(size_t)(k0 + ty + 8*i) * N + n0 + tx];
  __syncthreads();
#pragma unroll
  for (int i = 0; i < 4; ++i)
    dst[(size_t)(n0 + ty + 8*i) * K + k0 + tx] = (bf16)t[tx][ty + 8*i];
}

__global__ void concat_bias(const float* __restrict__ bq, const float* __restrict__ bk,
                            const float* __restrict__ bv, float* __restrict__ o)
{
  int i = blockIdx.x * 256 + threadIdx.x;
  o[i] = (i < 1024) ? bq[i] : (i < 2048 ? bk[i - 1024] : bv[i - 2048]);
}

// ---------------- LayerNorm 1: x fp32 -> h bf16 --------------------------------------
__global__ __launch_bounds__(256)
void ln1_kernel(const float* __restrict__ x, const float* __restrict__ gamma,
                bf16* __restrict__ out)
{
  __shared__ float2 red[4];
  const int row = blockIdx.x, tid = threadIdx.x;
  const float4 v = ((const float4*)(x + (size_t)row * DM))[tid];
  float s  = v.x + v.y + v.z + v.w;
  float s2 = v.x*v.x + v.y*v.y + v.z*v.z + v.w*v.w;
#pragma unroll
  for (int m = 32; m >= 1; m >>= 1) { s += __shfl_xor(s, m); s2 += __shfl_xor(s2, m); }
  if ((tid & 63) == 0) red[tid >> 6] = make_float2(s, s2);
  __syncthreads();
  float S  = red[0].x + red[1].x + red[2].x + red[3].x;
  float S2 = red[0].y + red[1].y + red[2].y + red[3].y;
  const float mean = S * (1.0f / DM);
  const float var  = S2 * (1.0f / DM) - mean * mean;
  const float rs   = rsqrtf(var + 1e-5f);
  const float4 g = ((const float4*)gamma)[tid];
  union { bf16 b[4]; uint2 u; } o;
  o.b[0] = (bf16)((v.x - mean) * rs * g.x);
  o.b[1] = (bf16)((v.y - mean) * rs * g.y);
  o.b[2] = (bf16)((v.z - mean) * rs * g.z);
  o.b[3] = (bf16)((v.w - mean) * rs * g.w);
  *(uint2*)(out + (size_t)row * DM + tid * 4) = o.u;
}

// ---------------- LayerNorm 2 (double LN): xnew fp32 -> h2 bf16 ----------------------
__global__ __launch_bounds__(256)
void ln2_kernel(const float* __restrict__ x, const float* __restrict__ gamma,
                const float* __restrict__ ffg, const float* __restrict__ ffb,
                bf16* __restrict__ out)
{
  __shared__ float2 red[4];
  const int row = blockIdx.x, tid = threadIdx.x;
  const float4 v = ((const float4*)(x + (size_t)row * DM))[tid];
  float s  = v.x + v.y + v.z + v.w;
  float s2 = v.x*v.x + v.y*v.y + v.z*v.z + v.w*v.w;
#pragma unroll
  for (int m = 32; m >= 1; m >>= 1) { s += __shfl_xor(s, m); s2 += __shfl_xor(s2, m); }
  if ((tid & 63) == 0) red[tid >> 6] = make_float2(s, s2);
  __syncthreads();
  float S  = red[0].x + red[1].x + red[2].x + red[3].x;
  float S2 = red[0].y + red[1].y + red[2].y + red[3].y;
  float mean = S * (1.0f / DM);
  float var  = S2 * (1.0f / DM) - mean * mean;
  float rs   = rsqrtf(var + 1e-5f);
  const float4 g = ((const float4*)ffg)[tid];
  const float4 gg = ((const float4*)gamma)[tid];
  float y0 = (v.x - mean) * rs * gg.x;
  float y1 = (v.y - mean) * rs * gg.y;
  float y2 = (v.z - mean) * rs * gg.z;
  float y3 = (v.w - mean) * rs * gg.w;
  __syncthreads();  // red[] reuse
  s  = y0 + y1 + y2 + y3;
  s2 = y0*y0 + y1*y1 + y2*y2 + y3*y3;
#pragma unroll
  for (int m = 32; m >= 1; m >>= 1) { s += __shfl_xor(s, m); s2 += __shfl_xor(s2, m); }
  if ((tid & 63) == 0) red[tid >> 6] = make_float2(s, s2);
  __syncthreads();
  S  = red[0].x + red[1].x + red[2].x + red[3].x;
  S2 = red[0].y + red[1].y + red[2].y + red[3].y;
  mean = S * (1.0f / DM);
  var  = S2 * (1.0f / DM) - mean * mean;
  rs   = rsqrtf(var + 1e-5f);
  const float4 bb = ((const float4*)ffb)[tid];
  union { bf16 b[4]; uint2 u; } o;
  o.b[0] = (bf16)((y0 - mean) * rs * g.x + bb.x);
  o.b[1] = (bf16)((y1 - mean) * rs * g.y + bb.y);
  o.b[2] = (bf16)((y2 - mean) * rs * g.z + bb.z);
  o.b[3] = (bf16)((y3 - mean) * rs * g.w + bb.w);
  *(uint2*)(out + (size_t)row * DM + tid * 4) = o.u;
}

// ======================= 128x128 m97-style GEMM (swizzle + 4 blocks/CU) ===============
// C[M x N] = A[M x K](bf16,lda) @ Bt[N x K]^T + bias ; EPI 0 bf16, 1 fp32+res, 2 gelu bf16
// 4 waves (2M x 2N), BK=64, single 32KB LDS buffer, 2 barriers/K-tile. Latency hiding
// via 4 independent blocks/CU. B-frags loaded per-j to keep VGPR+AGPR <= 128 (the
// 4-waves/SIMD threshold). LDS swizzle: granule g of row r stored from g^(r&7).

template<int EPI>
__global__ __launch_bounds__(256, 4)
void gemm128(const bf16* __restrict__ A, int lda,
             const bf16* __restrict__ Bt,
             const float* __restrict__ bias,
             const float* res, int ldres,
             void* Cout, int ldc, int K, int nblk)
{
  __shared__ __align__(16) bf16 lds[16384];   // 32 KB: A[128][64] | B[128][64]
  const int tid = threadIdx.x, lane = tid & 63, wave = tid >> 6;
  const int wm = wave >> 1, wn = wave & 1;
  const int l16 = lane & 15, lg = lane >> 4;

  // XCD-aware swizzle (nblk % 8 == 0); M = 16384 -> 128 row blocks
  int id = blockIdx.x;
  id = (id & 7) * (nblk >> 3) + (id >> 3);
  const int row0 = (id & 127) << 7;
  const int col0 = (id >> 7) << 7;
  const int NT = K >> 6;

  // ---- staging byte offsets (4 A-loads + 4 B-loads per thread; advance += 128 B) ----
  const char* Ab = (const char*)A;
  const char* Bb = (const char*)Bt;
  unsigned oA[4], oB[4];
  {
    const int lr = tid >> 3;          // 0..31 base row
    const int lc = tid & 7;           // granule slot
#pragma unroll
    for (int it = 0; it < 4; ++it) {
      const int r = it * 32 + lr;     // tile row 0..127
      const int gc = ((lc ^ (r & 7)) << 3);   // pre-swizzled source granule
      oA[it] = (unsigned)(((row0 + r) * lda + gc) * 2);
      oB[it] = (unsigned)(((col0 + r) * K   + gc) * 2);
    }
  }

#define STAGE() do { \
    gload_lds16((const bf16*)(Ab + oA[0]), lds        + tid * 8); \
    gload_lds16((const bf16*)(Ab + oA[1]), lds + 2048 + tid * 8); \
    gload_lds16((const bf16*)(Ab + oA[2]), lds + 4096 + tid * 8); \
    gload_lds16((const bf16*)(Ab + oA[3]), lds + 6144 + tid * 8); \
    gload_lds16((const bf16*)(Bb + oB[0]), lds + 8192 + tid * 8); \
    gload_lds16((const bf16*)(Bb + oB[1]), lds + 10240 + tid * 8); \
    gload_lds16((const bf16*)(Bb + oB[2]), lds + 12288 + tid * 8); \
    gload_lds16((const bf16*)(Bb + oB[3]), lds + 14336 + tid * 8); \
    oA[0] += 128; oA[1] += 128; oA[2] += 128; oA[3] += 128; \
    oB[0] += 128; oB[1] += 128; oB[2] += 128; oB[3] += 128; } while (0)

  // ---- frag LDS element offsets (iteration-invariant, swizzle baked in) ------------
  int aoff[4][2], boff[4][2];
#pragma unroll
  for (int i = 0; i < 4; ++i) {
    const int ra = wm * 64 + i * 16 + l16;
    const int rb = wn * 64 + i * 16 + l16;
#pragma unroll
    for (int kk = 0; kk < 2; ++kk) {
      aoff[i][kk] = ra * 64 + (((kk * 4 + lg) ^ (ra & 7)) << 3);
      boff[i][kk] = 8192 + rb * 64 + (((kk * 4 + lg) ^ (rb & 7)) << 3);
    }
  }

  f32x4 acc[4][4] = {};

  STAGE();                      // tile 0
  for (int t = 0; t < NT; ++t) {
    __syncthreads();            // drains vmcnt(0): tile t landed in LDS
    bf16x8 af[4][2];
#pragma unroll
    for (int i = 0; i < 4; ++i) {
      af[i][0] = *(const bf16x8*)&lds[aoff[i][0]];
      af[i][1] = *(const bf16x8*)&lds[aoff[i][1]];
    }
#pragma unroll
    for (int j = 0; j < 4; ++j) {
      bf16x8 b0 = *(const bf16x8*)&lds[boff[j][0]];
      bf16x8 b1 = *(const bf16x8*)&lds[boff[j][1]];
#pragma unroll
      for (int i = 0; i < 4; ++i) {
        acc[i][j] = __builtin_amdgcn_mfma_f32_16x16x32_bf16(af[i][0], b0, acc[i][j], 0, 0, 0);
        acc[i][j] = __builtin_amdgcn_mfma_f32_16x16x32_bf16(af[i][1], b1, acc[i][j], 0, 0, 0);
      }
    }
    __syncthreads();            // all waves done reading tile t
    if (t + 1 < NT) STAGE();
  }

  // ---- epilogue: per wave 64x64 at (row0+wm*64, col0+wn*64) ------------------------
#pragma unroll
  for (int i = 0; i < 4; ++i) {
    const int m0 = row0 + wm * 64 + i * 16 + lg * 4;
#pragma unroll
    for (int j = 0; j < 4; ++j) {
      const int n = col0 + wn * 64 + j * 16 + l16;
      const float bv = bias[n];
#pragma unroll
      for (int r = 0; r < 4; ++r) {
        const long m = m0 + r;
        float v = acc[i][j][r] + bv;
        if constexpr (EPI == 0) {
          ((bf16*)Cout)[m * ldc + n] = (bf16)v;
        } else if constexpr (EPI == 1) {
          ((float*)Cout)[m * ldc + n] = v + res[m * ldres + n];
        } else {
          float gl = 0.5f * v * (1.0f + erff(v * 0.70710678118654752f));
          ((bf16*)Cout)[m * ldc + n] = (bf16)gl;
        }
      }
    }
  }
}

// ---------------- dilated attention: one wave per (b, g, h) --------------------------
__global__ __launch_bounds__(64)
void attn_kernel(bf16* qkv)
{
  __shared__ bf16 Plds[32 * 32];
  __shared__ bf16 vT[64 * 32];
  const int blk = blockIdx.x;
  const int h = blk & 15;
  const int g = (blk >> 4) & 63;
  const int b = blk >> 10;
  const int par = h & 1;
  const int lane = threadIdx.x;
  const int l16 = lane & 15, lg = lane >> 4;
  const long base = ((long)b * 4096 + g * 64) * NQKV;

  bf16x8 qf[2][2], kf[2][2];
#pragma unroll
  for (int mb = 0; mb < 2; ++mb) {
    const int s = par + 2 * (mb * 16 + l16);
    const bf16* qrow = qkv + base + (long)s * NQKV + h * 64;
#pragma unroll
    for (int kk = 0; kk < 2; ++kk) {
      qf[mb][kk] = *(const bf16x8*)(qrow + kk * 32 + lg * 8);
      kf[mb][kk] = *(const bf16x8*)(qrow + 1024 + kk * 32 + lg * 8);
    }
  }

#pragma unroll
  for (int it = 0; it < 4; ++it) {
    const int kr  = it * 8 + (lane >> 3);
    const int dh0 = (lane & 7) * 8;
    const int s = par + 2 * kr;
    union { uint4 u; bf16 e[8]; } vv;
    vv.u = *(const uint4*)(qkv + base + (long)s * NQKV + 2048 + h * 64 + dh0);
#pragma unroll
    for (int j = 0; j < 8; ++j)
      vT[(dh0 + j) * 32 + kr] = vv.e[j];
  }

  f32x4 sc[2][2] = {};
#pragma unroll
  for (int mb = 0; mb < 2; ++mb)
#pragma unroll
    for (int nb = 0; nb < 2; ++nb)
#pragma unroll
      for (int kk = 0; kk < 2; ++kk)
        sc[mb][nb] = __builtin_amdgcn_mfma_f32_16x16x32_bf16(qf[mb][kk], kf[nb][kk], sc[mb][nb], 0, 0, 0);

  float pr[2][2][4];
#pragma unroll
  for (int mb = 0; mb < 2; ++mb)
#pragma unroll
    for (int r = 0; r < 4; ++r) {
      float a0 = sc[mb][0][r] * 0.125f, a1 = sc[mb][1][r] * 0.125f;
      float mx = fmaxf(a0, a1);
#pragma unroll
      for (int msk = 8; msk >= 1; msk >>= 1) mx = fmaxf(mx, __shfl_xor(mx, msk));
      float e0 = expf(a0 - mx), e1 = expf(a1 - mx);
      float sm = e0 + e1;
#pragma unroll
      for (int msk = 8; msk >= 1; msk >>= 1) sm += __shfl_xor(sm, msk);
      float inv = 1.0f / sm;
      pr[mb][0][r] = e0 * inv;
      pr[mb][1][r] = e1 * inv;
    }

  __syncthreads();
#pragma unroll
  for (int mb = 0; mb < 2; ++mb)
#pragma unroll
    for (int nb = 0; nb < 2; ++nb)
#pragma unroll
      for (int r = 0; r < 4; ++r)
        Plds[(mb * 16 + lg * 4 + r) * 32 + nb * 16 + l16] = (bf16)pr[mb][nb][r];
  __syncthreads();

  bf16x8 pa[2], vb[4];
#pragma unroll
  for (int mb = 0; mb < 2; ++mb)
    pa[mb] = *(const bf16x8*)&Plds[(mb * 16 + l16) * 32 + lg * 8];
#pragma unroll
  for (int nb = 0; nb < 4; ++nb)
    vb[nb] = *(const bf16x8*)&vT[(nb * 16 + l16) * 32 + lg * 8];
  f32x4 oc[2][4] = {};
#pragma unroll
  for (int mb = 0; mb < 2; ++mb)
#pragma unroll
    for (int nb = 0; nb < 4; ++nb)
      oc[mb][nb] = __builtin_amdgcn_mfma_f32_16x16x32_bf16(pa[mb], vb[nb], oc[mb][nb], 0, 0, 0);

#pragma unroll
  for (int mb = 0; mb < 2; ++mb)
#pragma unroll
    for (int nb = 0; nb < 4; ++nb)
#pragma unroll
      for (int r = 0; r < 4; ++r) {
        const int m = mb * 16 + lg * 4 + r;
        const int s = par + 2 * m;
        qkv[base + (long)s * NQKV + h * 64 + nb * 16 + l16] = (bf16)oc[mb][nb][r];
      }
  const uint4 z = make_uint4(0, 0, 0, 0);
#pragma unroll
  for (int it = 0; it < 4; ++it) {
    const int r2 = it * 8 + (lane >> 3);
    const int s = (1 - par) + 2 * r2;
    *(uint4*)(qkv + base + (long)s * NQKV + h * 64 + (lane & 7) * 8) = z;
  }
}

// ---------------- host-side orchestration --------------------------------------------
extern "C" void kernel_launch(void* const* d_in, const int* in_sizes, int n_in,
                              void* d_out, int out_size, void* d_ws, size_t ws_size,
                              hipStream_t stream)
{
  const float* x     = (const float*)d_in[0];
  const float* gamma = (const float*)d_in[1];
  const float* wq = (const float*)d_in[2];  const float* bq = (const float*)d_in[3];
  const float* wk = (const float*)d_in[4];  const float* bk = (const float*)d_in[5];
  const float* wv = (const float*)d_in[6];  const float* bv = (const float*)d_in[7];
  const float* wo = (const float*)d_in[8];  const float* bo = (const float*)d_in[9];
  const float* ffg = (const float*)d_in[10]; const float* ffb = (const float*)d_in[11];
  const float* w1 = (const float*)d_in[12]; const float* b1 = (const float*)d_in[13];
  const float* w2 = (const float*)d_in[14]; const float* b2 = (const float*)d_in[15];

  char* p = (char*)d_ws;
  bf16* Wqkv_t = (bf16*)p; p += (size_t)NQKV * DM * 2;
  bf16* Wo_t   = (bf16*)p; p += (size_t)DM * DM * 2;
  bf16* W1_t   = (bf16*)p; p += (size_t)DFF * DM * 2;
  bf16* W2_t   = (bf16*)p; p += (size_t)DM * DFF * 2;
  float* bqkv  = (float*)p; p += (size_t)NQKV * 4;
  bf16* hbuf   = (bf16*)p; p += (size_t)NTOK * DM * 2;
  bf16* qkv    = (bf16*)p; p += (size_t)NTOK * DFF * 2;
  float* xnew  = (float*)d_out;

  dim3 b256(256);
  transpose_cvt<<<dim3(32, 32),  b256, 0, stream>>>(wq, Wqkv_t,               DM, DM);
  transpose_cvt<<<dim3(32, 32),  b256, 0, stream>>>(wk, Wqkv_t + 1024 * 1024, DM, DM);
  transpose_cvt<<<dim3(32, 32),  b256, 0, stream>>>(wv, Wqkv_t + 2048 * 1024, DM, DM);
  transpose_cvt<<<dim3(32, 32),  b256, 0, stream>>>(wo, Wo_t, DM, DM);
  transpose_cvt<<<dim3(128, 32), b256, 0, stream>>>(w1, W1_t, DM, DFF);
  transpose_cvt<<<dim3(32, 128), b256, 0, stream>>>(w2, W2_t, DFF, DM);
  concat_bias<<<12, b256, 0, stream>>>(bq, bk, bv, bqkv);

  ln1_kernel<<<NTOK, b256, 0, stream>>>(x, gamma, hbuf);

  // QKV GEMM: h @ [wq|wk|wv] -> qkv bf16 [16384][3072]
  gemm128<0><<<dim3(128 * 24), b256, 0, stream>>>(
      hbuf, DM, Wqkv_t, bqkv, nullptr, 0, qkv, NQKV, DM, 128 * 24);

  attn_kernel<<<4096, dim3(64), 0, stream>>>(qkv);

  // WO GEMM + residual -> xnew fp32 (d_out)
  gemm128<1><<<dim3(128 * 8), b256, 0, stream>>>(
      qkv, NQKV, Wo_t, bo, x, DM, xnew, DM, DM, 128 * 8);

  ln2_kernel<<<NTOK, b256, 0, stream>>>(xnew, gamma, ffg, ffb, hbuf);

  // FFN1 + GELU -> g1 bf16 [16384][4096]
  gemm128<2><<<dim3(128 * 32), b256, 0, stream>>>(
      hbuf, DM, W1_t, b1, nullptr, 0, qkv, DFF, DM, 128 * 32);

  // FFN2 + residual -> d_out fp32
  gemm128<1><<<dim3(128 * 8), b256, 0, stream>>>(
      qkv, DFF, W2_t, b2, xnew, DM, (float*)d_out, DM, DFF, 128 * 8);
}